// Round 8
// baseline (773.835 us; speedup 1.0000x reference)
//
#include <hip/hip_runtime.h>
#include <cstdint>
#include <cstddef>

// Problem dims (fixed). Inputs fp32, output fp32.
#define B_DIM 1024
#define T_DIM 32
#define V_DIM 1024
#define E_DIM 512
#define H_DIM 1024
#define O_DIM 1024

typedef unsigned short u16;
typedef __attribute__((ext_vector_type(8))) __bf16 bf16x8;  // MFMA A/B frag
typedef __attribute__((ext_vector_type(4))) float f32x4;    // MFMA C/D frag
typedef __attribute__((ext_vector_type(4))) unsigned int u32x4;  // asm-safe 16B

__device__ __forceinline__ float bf2f(u16 u) {
  union { unsigned int i; float f; } v; v.i = ((unsigned int)u) << 16; return v.f;
}
__device__ __forceinline__ u16 f2bf(float f) {
  union { float f; unsigned int i; } v; v.f = f;
  return (u16)((v.i + 0x7fffu + ((v.i >> 16) & 1u)) >> 16);  // RNE
}
// async global->LDS, 16B/lane; HW writes lds_base + lane*16 (wave-uniform base)
__device__ __forceinline__ void async_cp16(const void* g, void* l) {
  __builtin_amdgcn_global_load_lds(
      (const __attribute__((address_space(1))) void*)g,
      (__attribute__((address_space(3))) void*)l, 16, 0, 0);
}
// fast tanh via hw exp+rcp: exact at +-inf, |err| ~1e-6 (<< bf16 ulp)
__device__ __forceinline__ float fast_tanh(float v) {
  return 1.f - 2.f / (__expf(2.f * v) + 1.f);
}

// ---------------------------------------------------------------------------
// Convert W_hh, W_out (and msg if dmsg != null) fp32 -> bf16, grid-stride.
// ---------------------------------------------------------------------------
__global__ __launch_bounds__(256) void convert_all(
    const float* __restrict__ Whh, const float* __restrict__ Wout,
    const float* __restrict__ msg, u16* __restrict__ dWhh,
    u16* __restrict__ dWout, u16* __restrict__ dmsg) {
  const int QW = 262144;            // 1M elems / 4
  const int QM = 8388608;           // 32M elems / 4
  const int total = dmsg ? (2 * QW + QM) : (2 * QW);
  int i = blockIdx.x * 256 + threadIdx.x;
  const int stride = gridDim.x * 256;
  for (; i < total; i += stride) {
    const float4* src; ushort4* dst; int j;
    if (i < QW)            { src = (const float4*)Whh;  dst = (ushort4*)dWhh;  j = i; }
    else if (i < 2 * QW)   { src = (const float4*)Wout; dst = (ushort4*)dWout; j = i - QW; }
    else                   { src = (const float4*)msg;  dst = (ushort4*)dmsg;  j = i - 2 * QW; }
    float4 v = src[j];
    ushort4 o = {f2bf(v.x), f2bf(v.y), f2bf(v.z), f2bf(v.w)};
    dst[j] = o;
  }
}

// ---------------------------------------------------------------------------
// W_comb[h][v] = sum_e W_ih[h][e] * W_emb[e][v]  (VALU, verified)
// ---------------------------------------------------------------------------
__global__ __launch_bounds__(256) void wcomb_valu(
    const float* __restrict__ Wih, const float* __restrict__ Wemb,
    u16* __restrict__ Wc) {
  __shared__ __align__(16) float As[16][68];
  __shared__ __align__(16) float Bs[16][68];
  const int tx = threadIdx.x & 15, ty = threadIdx.x >> 4;
  const int v0 = blockIdx.x * 64, h0 = blockIdx.y * 64;
  float acc[4][4] = {};
  for (int kt = 0; kt < 32; ++kt) {  // K = 512
#pragma unroll
    for (int i = 0; i < 4; ++i) {
      int idx = threadIdx.x + i * 256;
      int row = idx >> 4, k = idx & 15;
      As[k][row] = Wih[(size_t)(h0 + row) * E_DIM + kt * 16 + k];
      Bs[k][row] = Wemb[(size_t)(kt * 16 + k) * V_DIM + v0 + row];
    }
    __syncthreads();
    for (int k = 0; k < 16; ++k) {
      float4 a = *(const float4*)&As[k][ty * 4];
      float4 b = *(const float4*)&Bs[k][tx * 4];
      const float av[4] = {a.x, a.y, a.z, a.w}, bv[4] = {b.x, b.y, b.z, b.w};
#pragma unroll
      for (int i = 0; i < 4; ++i)
#pragma unroll
        for (int j = 0; j < 4; ++j) acc[i][j] += av[i] * bv[j];
    }
    __syncthreads();
  }
#pragma unroll
  for (int i = 0; i < 4; ++i)
#pragma unroll
    for (int j = 0; j < 4; ++j)
      Wc[(size_t)(h0 + ty * 4 + i) * V_DIM + v0 + tx * 4 + j] = f2bf(acc[i][j]);
}

// b_comb[h] = W_ih[h,:].b_emb + b_ih[h]; block 0 zeroes the step counter
__global__ __launch_bounds__(256) void bcomb_valu(
    const float* __restrict__ Wih, const float* __restrict__ bemb,
    const float* __restrict__ bih, float* __restrict__ bc,
    unsigned* __restrict__ ctr) {
  if (blockIdx.x == 0 && threadIdx.x == 0) *ctr = 0;
  int h = blockIdx.x * 256 + threadIdx.x;  // grid 4
  float s = 0.f;
  for (int e = 0; e < E_DIM; ++e) s += Wih[(size_t)h * E_DIM + e] * bemb[e];
  bc[h] = s + bih[h];
}

// ---------------------------------------------------------------------------
// xproj GEMM (verified R6/R7, 92 us): 128x128 tiles, depth-3 counted vmcnt,
// XOR-swizzled LDS, XCD band remap. out = msgb . Wc^T + bc -> xp scatter.
// ---------------------------------------------------------------------------
__global__ __launch_bounds__(256) void gemm_xp(
    const u16* __restrict__ A, const u16* __restrict__ Bm,
    const float* __restrict__ bias, u16* __restrict__ outp) {
  __shared__ __align__(16) u16 lds[49152];
  const int tid = threadIdx.x, lane = tid & 63, w = tid >> 6;
  const int lrow = lane >> 4, lcol = lane & 15;
  const int l7 = lane & 7, r8 = lane >> 3;
  const int p = blockIdx.x;
  const int xk = p & 7, q = p >> 3;
  const int mt = xk * 32 + (q >> 3), nt = q & 7;
  const int m0 = mt * 128, n0 = nt * 128;
  const int mq = (w & 1) * 64, nq = (w >> 1) * 64;
  const int half = w >> 1, wv = w & 1;  // waves 0,1 stage A; 2,3 stage B

  auto stage = [&](int kk, int d) {
    const u16* src = half ? Bm : A;
    const int rbase = half ? n0 : m0;
#pragma unroll
    for (int i = 0; i < 8; ++i) {
      int row = wv * 64 + i * 8 + r8;
      async_cp16(src + (size_t)(rbase + row) * H_DIM + kk * 64 + ((l7 ^ r8) << 3),
                 lds + d * 16384 + half * 8192 + (wv * 64 + i * 8) * 64);
    }
  };

  f32x4 acc[4][4] = {};
  auto kchunk = [&](int d) {
    const u16* base = lds + d * 16384;
#pragma unroll
    for (int ks = 0; ks < 2; ++ks) {
      const int ce = ks * 32 + lrow * 8;
      bf16x8 a[4], b[4];
#pragma unroll
      for (int i = 0; i < 4; ++i) {
        int row = mq + i * 16 + lcol;
        a[i] = *(const bf16x8*)(base + row * 64 + (ce ^ ((row & 7) << 3)));
      }
#pragma unroll
      for (int i = 0; i < 4; ++i) {
        int row = nq + i * 16 + lcol;
        b[i] = *(const bf16x8*)(base + 8192 + row * 64 + (ce ^ ((row & 7) << 3)));
      }
#pragma unroll
      for (int i = 0; i < 4; ++i)
#pragma unroll
        for (int j = 0; j < 4; ++j)
          acc[i][j] = __builtin_amdgcn_mfma_f32_16x16x32_bf16(a[i], b[j], acc[i][j], 0, 0, 0);
    }
  };

  stage(0, 0); stage(1, 1); stage(2, 2);
#pragma unroll
  for (int kk = 0; kk < 16; ++kk) {
    if (kk <= 13)      asm volatile("s_waitcnt vmcnt(16)" ::: "memory");
    else if (kk == 14) asm volatile("s_waitcnt vmcnt(8)" ::: "memory");
    else               asm volatile("s_waitcnt vmcnt(0)" ::: "memory");
    __builtin_amdgcn_s_barrier();
    kchunk(kk % 3);
    __builtin_amdgcn_s_barrier();
    if (kk <= 12) stage(kk + 3, kk % 3);
  }

  float bv[4];
#pragma unroll
  for (int j = 0; j < 4; ++j) bv[j] = bias[n0 + nq + j * 16 + lcol];
#pragma unroll
  for (int i = 0; i < 4; ++i)
#pragma unroll
    for (int rr = 0; rr < 4; ++rr) {
      int rg = m0 + mq + i * 16 + lrow * 4 + rr;  // flat (b*T + t)
      int bI = rg >> 5, tI = rg & 31;
      u16* dst = outp + ((size_t)tI * B_DIM + bI) * H_DIM + n0 + nq;
#pragma unroll
      for (int j = 0; j < 4; ++j)
        dst[j * 16 + lcol] = f2bf(acc[i][j][rr] + bv[j]);
    }
}

// ---------------------------------------------------------------------------
// FUSED 8-step RNN kernel. Grid 256 (1/CU, cooperative), 64x64 tiles,
// mt=(p&7)*2+(q>>4): each XCD owns 2 m-bands -> A/W reads stay in its L2.
// Inter-step hand-off WITHOUT kernel boundary:
//  - h[t] overlays xp[t]; internal steps store via sc0|sc1 write-through
//    (device-coherent, 16B, NOT atomic -> full-speed, R3's RMW-store trap
//    avoided); last step of chunk: plain stores + kernel boundary.
//  - x_t read with sc0|sc1 LOADS (no L2 pollution of lines later overlaid).
//  - barrier: one fetch_add per block on a cumulative counter (RMW executes
//    at coherence point -> prompt visibility), tid0 polls, syncthreads.
// K-loop: verified depth-3 counted-vmcnt (xv issued oldest; counts exact).
// ---------------------------------------------------------------------------
__global__ __launch_bounds__(256) void steps8(
    const u16* __restrict__ Bm, u16* __restrict__ xp,
    const float* __restrict__ bhh, unsigned* __restrict__ ctr, int t0) {
  __shared__ __align__(16) u16 lds[24576];  // 3 x 8KB chunk bufs
  const int tid = threadIdx.x, lane = tid & 63, w = tid >> 6;
  const int lrow = lane >> 4, lcol = lane & 15;
  const int l7 = lane & 7, r8 = lane >> 3;
  const int p = blockIdx.x;
  const int xcd = p & 7, q = p >> 3;
  const int mt = xcd * 2 + (q >> 4), nt = q & 15;
  const int m0 = mt * 64, n0 = nt * 64;
  const int mq = (w & 1) * 32, nq = (w >> 1) * 32;
  const int half = w >> 1, wv = w & 1;
  const float bv0 = bhh[n0 + nq + lcol], bv1 = bhh[n0 + nq + 16 + lcol];
  const int xrow = tid >> 2, xce = (tid & 3) * 16;  // store-layout row/cols

  for (int s = 0; s < 8; ++s) {
    const int t = t0 + s;
    u16* slot = xp + (size_t)t * (B_DIM * H_DIM);        // x_t, becomes h[t]
    const u16* A = (t == 0) ? nullptr : xp + (size_t)(t - 1) * (B_DIM * H_DIM);

    // x_t own-tile: device-coherent loads, issued FIRST (oldest in vm queue)
    const u16* xgp = slot + (size_t)(m0 + xrow) * H_DIM + n0 + xce;
    u32x4 xv0, xv1;
    asm volatile(
        "global_load_dwordx4 %0, %2, off sc0 sc1\n\t"
        "global_load_dwordx4 %1, %3, off sc0 sc1"
        : "=v"(xv0), "=v"(xv1)
        : "v"(xgp), "v"(xgp + 8)
        : "memory");

    f32x4 acc[2][2] = {};
    if (A != nullptr) {
      auto stage = [&](int kk, int d) {
        const u16* src = half ? Bm : A;
        const int rbase = half ? n0 : m0;
#pragma unroll
        for (int i = 0; i < 4; ++i) {
          int row = wv * 32 + i * 8 + r8;
          async_cp16(src + (size_t)(rbase + row) * H_DIM + kk * 64 + ((l7 ^ r8) << 3),
                     lds + d * 8192 + half * 4096 + (wv * 32 + i * 8) * 64);
        }
      };
      stage(0, 0); stage(1, 1); stage(2, 2);
#pragma unroll
      for (int kk = 0; kk < 16; ++kk) {
        // per-thread outstanding at wait: 2(xv)+12 -> vmcnt(8) drains xv+chunk0
        if (kk <= 13)      asm volatile("s_waitcnt vmcnt(8)" ::: "memory");
        else if (kk == 14) asm volatile("s_waitcnt vmcnt(4)" ::: "memory");
        else               asm volatile("s_waitcnt vmcnt(0)" ::: "memory");
        __builtin_amdgcn_s_barrier();   // chunk kk LDS-visible
        {
          const u16* base = lds + (kk % 3) * 8192;
#pragma unroll
          for (int ks = 0; ks < 2; ++ks) {
            const int ce = ks * 32 + lrow * 8;
            bf16x8 a0, a1, b0, b1;
            {
              int rA0 = mq + lcol, rA1 = mq + 16 + lcol;
              int rB0 = nq + lcol, rB1 = nq + 16 + lcol;
              a0 = *(const bf16x8*)(base + rA0 * 64 + (ce ^ ((rA0 & 7) << 3)));
              a1 = *(const bf16x8*)(base + rA1 * 64 + (ce ^ ((rA1 & 7) << 3)));
              b0 = *(const bf16x8*)(base + 4096 + rB0 * 64 + (ce ^ ((rB0 & 7) << 3)));
              b1 = *(const bf16x8*)(base + 4096 + rB1 * 64 + (ce ^ ((rB1 & 7) << 3)));
            }
            acc[0][0] = __builtin_amdgcn_mfma_f32_16x16x32_bf16(a0, b0, acc[0][0], 0, 0, 0);
            acc[0][1] = __builtin_amdgcn_mfma_f32_16x16x32_bf16(a0, b1, acc[0][1], 0, 0, 0);
            acc[1][0] = __builtin_amdgcn_mfma_f32_16x16x32_bf16(a1, b0, acc[1][0], 0, 0, 0);
            acc[1][1] = __builtin_amdgcn_mfma_f32_16x16x32_bf16(a1, b1, acc[1][1], 0, 0, 0);
          }
        }
        __builtin_amdgcn_s_barrier();   // reads of buf kk%3 done
        if (kk <= 12) stage(kk + 3, kk % 3);
      }
    } else {
      asm volatile("s_waitcnt vmcnt(0)" ::: "memory");  // xv arrived
      __builtin_amdgcn_s_barrier();
    }

    // park xv into buf1 (free after k-loop), epilogue into buf0
    *(u32x4*)(lds + 8192 + xrow * 64 + xce) = xv0;
    *(u32x4*)(lds + 8192 + xrow * 64 + xce + 8) = xv1;
    __syncthreads();
#pragma unroll
    for (int i = 0; i < 2; ++i)
#pragma unroll
      for (int rr = 0; rr < 4; ++rr) {
        int rowl = mq + i * 16 + lrow * 4 + rr;
#pragma unroll
        for (int j = 0; j < 2; ++j) {
          int col = nq + j * 16 + lcol;
          float v = acc[i][j][rr] + (j ? bv1 : bv0) + bf2f(lds[8192 + rowl * 64 + col]);
          lds[rowl * 64 + col] = f2bf(fast_tanh(v));
        }
      }
    __syncthreads();
    {
      const u32x4* sp = (const u32x4*)(lds + xrow * 64 + xce);
      u32x4 h0 = sp[0], h1 = sp[1];
      u16* gp = slot + (size_t)(m0 + xrow) * H_DIM + n0 + xce;
      if (s < 7) {
        // device-coherent write-through (visible without kernel boundary)
        asm volatile(
            "global_store_dwordx4 %0, %2, off sc0 sc1\n\t"
            "global_store_dwordx4 %1, %3, off sc0 sc1"
            :: "v"(gp), "v"(gp + 8), "v"(h0), "v"(h1)
            : "memory");
        asm volatile("s_waitcnt vmcnt(0)" ::: "memory");
        __syncthreads();                 // all waves' stores drained
        if (tid == 0) {
          const unsigned tgt = 256u * (unsigned)(7 * (t0 >> 3) + s + 1);
          __hip_atomic_fetch_add(ctr, 1u, __ATOMIC_RELAXED,
                                 __HIP_MEMORY_SCOPE_AGENT);
          while (__hip_atomic_load(ctr, __ATOMIC_RELAXED,
                                   __HIP_MEMORY_SCOPE_AGENT) < tgt)
            __builtin_amdgcn_s_sleep(4);
        }
        __syncthreads();                 // release block for step s+1
      } else {
        // last step of chunk: plain stores; kernel boundary provides sync
        *(u32x4*)gp = h0;
        *(u32x4*)(gp + 8) = h1;
      }
    }
  }
}

// ---------------------------------------------------------------------------
// Output GEMM (verified R7 structure): out = h31 . Wout^T + bout, fp32.
// 64x64 tiles, grid 256, depth-3 counted vmcnt, swizzled LDS.
// ---------------------------------------------------------------------------
__global__ __launch_bounds__(256) void out_gemm(
    const u16* __restrict__ A, const u16* __restrict__ Bm,
    const float* __restrict__ bias, float* __restrict__ outp) {
  __shared__ __align__(16) u16 lds[24576];
  const int tid = threadIdx.x, lane = tid & 63, w = tid >> 6;
  const int lrow = lane >> 4, lcol = lane & 15;
  const int l7 = lane & 7, r8 = lane >> 3;
  const int p = blockIdx.x;
  const int xcd = p & 7, q = p >> 3;
  const int mt = xcd * 2 + (q >> 4), nt = q & 15;
  const int m0 = mt * 64, n0 = nt * 64;
  const int mq = (w & 1) * 32, nq = (w >> 1) * 32;
  const int half = w >> 1, wv = w & 1;

  auto stage = [&](int kk, int d) {
    const u16* src = half ? Bm : A;
    const int rbase = half ? n0 : m0;
#pragma unroll
    for (int i = 0; i < 4; ++i) {
      int row = wv * 32 + i * 8 + r8;
      async_cp16(src + (size_t)(rbase + row) * H_DIM + kk * 64 + ((l7 ^ r8) << 3),
                 lds + d * 8192 + half * 4096 + (wv * 32 + i * 8) * 64);
    }
  };
  f32x4 acc[2][2] = {};
  auto kchunk = [&](int d) {
    const u16* base = lds + d * 8192;
#pragma unroll
    for (int ks = 0; ks < 2; ++ks) {
      const int ce = ks * 32 + lrow * 8;
      int rA0 = mq + lcol, rA1 = mq + 16 + lcol;
      int rB0 = nq + lcol, rB1 = nq + 16 + lcol;
      bf16x8 a0 = *(const bf16x8*)(base + rA0 * 64 + (ce ^ ((rA0 & 7) << 3)));
      bf16x8 a1 = *(const bf16x8*)(base + rA1 * 64 + (ce ^ ((rA1 & 7) << 3)));
      bf16x8 b0 = *(const bf16x8*)(base + 4096 + rB0 * 64 + (ce ^ ((rB0 & 7) << 3)));
      bf16x8 b1 = *(const bf16x8*)(base + 4096 + rB1 * 64 + (ce ^ ((rB1 & 7) << 3)));
      acc[0][0] = __builtin_amdgcn_mfma_f32_16x16x32_bf16(a0, b0, acc[0][0], 0, 0, 0);
      acc[0][1] = __builtin_amdgcn_mfma_f32_16x16x32_bf16(a0, b1, acc[0][1], 0, 0, 0);
      acc[1][0] = __builtin_amdgcn_mfma_f32_16x16x32_bf16(a1, b0, acc[1][0], 0, 0, 0);
      acc[1][1] = __builtin_amdgcn_mfma_f32_16x16x32_bf16(a1, b1, acc[1][1], 0, 0, 0);
    }
  };
  stage(0, 0); stage(1, 1); stage(2, 2);
#pragma unroll
  for (int kk = 0; kk < 16; ++kk) {
    if (kk <= 13)      asm volatile("s_waitcnt vmcnt(8)" ::: "memory");
    else if (kk == 14) asm volatile("s_waitcnt vmcnt(4)" ::: "memory");
    else               asm volatile("s_waitcnt vmcnt(0)" ::: "memory");
    __builtin_amdgcn_s_barrier();
    kchunk(kk % 3);
    __builtin_amdgcn_s_barrier();
    if (kk <= 12) stage(kk + 3, kk % 3);
  }
  float bv[2] = {bias[n0 + nq + lcol], bias[n0 + nq + 16 + lcol]};
#pragma unroll
  for (int i = 0; i < 2; ++i)
#pragma unroll
    for (int rr = 0; rr < 4; ++rr) {
      int row = m0 + mq + i * 16 + lrow * 4 + rr;
#pragma unroll
      for (int j = 0; j < 2; ++j)
        outp[(size_t)row * O_DIM + n0 + nq + j * 16 + lcol] =
            acc[i][j][rr] + bv[j];
    }
}

// ---------------------------------------------------------------------------
// FALLBACK xproj (verified R5) for small workspace: fp32 A reg-staged.
// ---------------------------------------------------------------------------
__global__ __launch_bounds__(256) void xproj_mfma(
    const float* __restrict__ msg, const u16* __restrict__ Wc,
    const float* __restrict__ bc, u16* __restrict__ xp) {
  __shared__ u16 As[128 * 64];
  __shared__ u16 Bs[128 * 64];
  const int tid = threadIdx.x, lane = tid & 63, w = tid >> 6;
  const int lrow = lane >> 4, lcol = lane & 15;
  const int p = blockIdx.y * gridDim.x + blockIdx.x;
  const int xk = p & 7, q = p >> 3;
  const int m0 = (xk * 32 + (q >> 3)) * 128;
  const int n0 = (q & 7) * 128;
  const int mq = (w & 1) * 64, nq = (w >> 1) * 64;
  f32x4 acc[4][4] = {};
  const int r8 = lane >> 3, l7 = lane & 7;
  const int ar = tid >> 1, ak = (tid & 1) * 32;

  auto stageB = [&](int kk) {
#pragma unroll
    for (int i = 0; i < 4; ++i) {
      int ch = w * 4 + i;
      async_cp16(Wc + (size_t)(n0 + ch * 8 + r8) * V_DIM + kk * 64 + ((l7 ^ r8) << 3),
                 Bs + ch * 512);
    }
  };
  float4 areg[8];
  auto loadA = [&](int kk) {
    const float4* src = (const float4*)(msg + (size_t)(m0 + ar) * V_DIM + kk * 64 + ak);
#pragma unroll
    for (int i = 0; i < 8; ++i) areg[i] = src[i];
  };
  auto writeA = [&]() {
    u16 tmp[32];
#pragma unroll
    for (int i = 0; i < 8; ++i) {
      tmp[i * 4 + 0] = f2bf(areg[i].x);
      tmp[i * 4 + 1] = f2bf(areg[i].y);
      tmp[i * 4 + 2] = f2bf(areg[i].z);
      tmp[i * 4 + 3] = f2bf(areg[i].w);
    }
#pragma unroll
    for (int i = 0; i < 4; ++i) {
      int c = (ak + i * 8) ^ ((ar & 7) << 3);
      *(uint4*)(As + (size_t)ar * 64 + c) = *(const uint4*)(tmp + i * 8);
    }
  };

  loadA(0);
  stageB(0);
  writeA();
  for (int kk = 0; kk < 16; ++kk) {
    __syncthreads();
    if (kk < 15) loadA(kk + 1);
#pragma unroll
    for (int ks = 0; ks < 2; ++ks) {
      const int kb = ks * 32 + lrow * 8;
      bf16x8 a[4], b[4];
#pragma unroll
      for (int i = 0; i < 4; ++i) {
        int row = mq + i * 16 + lcol;
        a[i] = *(const bf16x8*)(As + row * 64 + (kb ^ ((row & 7) << 3)));
      }
#pragma unroll
      for (int i = 0; i < 4; ++i) {
        int row = nq + i * 16 + lcol;
        b[i] = *(const bf16x8*)(Bs + row * 64 + (kb ^ ((row & 7) << 3)));
      }
#pragma unroll
      for (int i = 0; i < 4; ++i)
#pragma unroll
        for (int j = 0; j < 4; ++j)
          acc[i][j] = __builtin_amdgcn_mfma_f32_16x16x32_bf16(a[i], b[j], acc[i][j], 0, 0, 0);
    }
    __syncthreads();
    if (kk < 15) { stageB(kk + 1); writeA(); }
  }
  float bcv[4];
#pragma unroll
  for (int j = 0; j < 4; ++j) bcv[j] = bc[n0 + nq + j * 16 + lcol];
#pragma unroll
  for (int i = 0; i < 4; ++i)
#pragma unroll
    for (int rr = 0; rr < 4; ++rr) {
      int rg = m0 + mq + i * 16 + lrow * 4 + rr;
      int bI = rg >> 5, tI = rg & 31;
      u16* dst = xp + ((size_t)tI * B_DIM + bI) * H_DIM + n0 + nq;
#pragma unroll
      for (int j = 0; j < 4; ++j)
        dst[j * 16 + lcol] = f2bf(acc[i][j][rr] + bcv[j]);
    }
}

// ---------------------------------------------------------------------------
extern "C" void kernel_launch(void* const* d_in, const int* in_sizes, int n_in,
                              void* d_out, int out_size, void* d_ws, size_t ws_size,
                              hipStream_t stream) {
  const float* msg  = (const float*)d_in[0];
  const float* Wemb = (const float*)d_in[1];
  const float* bemb = (const float*)d_in[2];
  const float* Wih  = (const float*)d_in[3];
  const float* bih  = (const float*)d_in[4];
  const float* Whh  = (const float*)d_in[5];
  const float* bhh  = (const float*)d_in[6];
  const float* Wout = (const float*)d_in[7];
  const float* bout = (const float*)d_in[8];
  char* ws = (char*)d_ws;

  // ws layout (bytes)
  float* bc     = (float*)ws;               // 4 KB
  u16* Wc       = (u16*)(ws + 4096);        // 2 MB
  u16* Whh_b    = (u16*)(ws + 2101248);     // 2 MB
  u16* Wout_b   = (u16*)(ws + 4198400);     // 2 MB
  unsigned* ctr = (unsigned*)(ws + 6295552);// 4 B (step barrier counter)
  u16* xp       = (u16*)(ws + 10489856);    // 64 MB (xp[t] becomes h[t])
  u16* msgb     = (u16*)(ws + 77598720);    // 64 MB (only if ws big enough)
  const size_t NEED_SMALL = 77598720;
  const size_t NEED_BIG   = 77598720 + 67108864;
  if (ws_size < NEED_SMALL) return;
  const bool big = ws_size >= NEED_BIG;

  if (big) {
    convert_all<<<2048, 256, 0, stream>>>(Whh, Wout, msg, Whh_b, Wout_b, msgb);
  } else {
    convert_all<<<512, 256, 0, stream>>>(Whh, Wout, nullptr, Whh_b, Wout_b, nullptr);
  }
  wcomb_valu<<<dim3(16, 16), 256, 0, stream>>>(Wih, Wemb, Wc);
  bcomb_valu<<<4, 256, 0, stream>>>(Wih, bemb, bih, bc, ctr);

  if (big) {
    gemm_xp<<<2048, 256, 0, stream>>>(msgb, Wc, bc, xp);
  } else {
    xproj_mfma<<<dim3(8, 256), 256, 0, stream>>>(msg, Wc, bc, xp);
  }

  // 32 RNN steps in 4 cooperative launches of 8 fused steps each
  for (int c = 0; c < 4; ++c) {
    const u16* a_w = Whh_b; u16* a_xp = xp; const float* a_b = bhh;
    unsigned* a_c = ctr; int a_t0 = c * 8;
    void* kargs[] = {(void*)&a_w, (void*)&a_xp, (void*)&a_b,
                     (void*)&a_c, (void*)&a_t0};
    (void)hipLaunchCooperativeKernel((const void*)steps8, dim3(256), dim3(256),
                                     kargs, 0, stream);
  }
  // out = h31 . W_out^T + b_out (h31 lives in xp slot 31)
  out_gemm<<<256, 256, 0, stream>>>(xp + (size_t)31 * B_DIM * H_DIM, Wout_b,
                                    bout, (float*)d_out);
}

// Round 9
// 546.815 us; speedup vs baseline: 1.4152x; 1.4152x over previous
//
#include <hip/hip_runtime.h>
#include <cstdint>
#include <cstddef>

// Problem dims (fixed). Inputs fp32, output fp32.
#define B_DIM 1024
#define T_DIM 32
#define V_DIM 1024
#define E_DIM 512
#define H_DIM 1024
#define O_DIM 1024

typedef unsigned short u16;
typedef __attribute__((ext_vector_type(8))) __bf16 bf16x8;  // MFMA A/B frag
typedef __attribute__((ext_vector_type(4))) float f32x4;    // MFMA C/D frag

__device__ __forceinline__ float bf2f(u16 u) {
  union { unsigned int i; float f; } v; v.i = ((unsigned int)u) << 16; return v.f;
}
__device__ __forceinline__ u16 f2bf(float f) {
  union { float f; unsigned int i; } v; v.f = f;
  return (u16)((v.i + 0x7fffu + ((v.i >> 16) & 1u)) >> 16);  // RNE
}
// async global->LDS, 16B/lane; HW writes lds_base + lane*16 (wave-uniform base)
__device__ __forceinline__ void async_cp16(const void* g, void* l) {
  __builtin_amdgcn_global_load_lds(
      (const __attribute__((address_space(1))) void*)g,
      (__attribute__((address_space(3))) void*)l, 16, 0, 0);
}
// fast tanh via hw exp+rcp: exact at +-inf, |err| ~1e-6 (<< bf16 ulp)
__device__ __forceinline__ float fast_tanh(float v) {
  return 1.f - 2.f / (__expf(2.f * v) + 1.f);
}

// ---------------------------------------------------------------------------
// Fused prep: blocks [0,2048) convert W_hh/W_out/msg fp32->bf16 (grid-stride),
// blocks [2048,2304) wcomb (W_comb = W_ih.W_emb), blocks [2304,2308) bcomb.
// One launch instead of three; convert BW overlaps wcomb VALU.
// ---------------------------------------------------------------------------
__global__ __launch_bounds__(256) void prep_all(
    const float* __restrict__ Whh, const float* __restrict__ Wout,
    const float* __restrict__ msg, const float* __restrict__ Wih,
    const float* __restrict__ Wemb, const float* __restrict__ bemb,
    const float* __restrict__ bih, u16* __restrict__ dWhh,
    u16* __restrict__ dWout, u16* __restrict__ dmsg,
    u16* __restrict__ Wc, float* __restrict__ bc) {
  __shared__ __align__(16) float As[16][68];
  __shared__ __align__(16) float Bs[16][68];
  const int bid = blockIdx.x;
  if (bid < 2048) {  // ---- convert ----
    const int QW = 262144;            // 1M elems / 4
    const int QM = 8388608;           // 32M elems / 4
    const int total = dmsg ? (2 * QW + QM) : (2 * QW);
    int i = bid * 256 + threadIdx.x;
    const int stride = 2048 * 256;
    for (; i < total; i += stride) {
      const float4* src; ushort4* dst; int j;
      if (i < QW)          { src = (const float4*)Whh;  dst = (ushort4*)dWhh;  j = i; }
      else if (i < 2 * QW) { src = (const float4*)Wout; dst = (ushort4*)dWout; j = i - QW; }
      else                 { src = (const float4*)msg;  dst = (ushort4*)dmsg;  j = i - 2 * QW; }
      float4 v = src[j];
      ushort4 o = {f2bf(v.x), f2bf(v.y), f2bf(v.z), f2bf(v.w)};
      dst[j] = o;
    }
  } else if (bid < 2304) {  // ---- wcomb (verified R4/R5 structure) ----
    const int b2 = bid - 2048;
    const int tx = threadIdx.x & 15, ty = threadIdx.x >> 4;
    const int v0 = (b2 & 15) * 64, h0 = (b2 >> 4) * 64;
    float acc[4][4] = {};
    for (int kt = 0; kt < 32; ++kt) {  // K = 512
#pragma unroll
      for (int i = 0; i < 4; ++i) {
        int idx = threadIdx.x + i * 256;
        int row = idx >> 4, k = idx & 15;
        As[k][row] = Wih[(size_t)(h0 + row) * E_DIM + kt * 16 + k];
        Bs[k][row] = Wemb[(size_t)(kt * 16 + k) * V_DIM + v0 + row];
      }
      __syncthreads();
      for (int k = 0; k < 16; ++k) {
        float4 a = *(const float4*)&As[k][ty * 4];
        float4 b = *(const float4*)&Bs[k][tx * 4];
        const float av[4] = {a.x, a.y, a.z, a.w}, bv[4] = {b.x, b.y, b.z, b.w};
#pragma unroll
        for (int i = 0; i < 4; ++i)
#pragma unroll
          for (int j = 0; j < 4; ++j) acc[i][j] += av[i] * bv[j];
      }
      __syncthreads();
    }
#pragma unroll
    for (int i = 0; i < 4; ++i)
#pragma unroll
      for (int j = 0; j < 4; ++j)
        Wc[(size_t)(h0 + ty * 4 + i) * V_DIM + v0 + tx * 4 + j] = f2bf(acc[i][j]);
  } else {  // ---- bcomb ----
    int h = (bid - 2304) * 256 + threadIdx.x;
    float s = 0.f;
    for (int e = 0; e < E_DIM; ++e) s += Wih[(size_t)h * E_DIM + e] * bemb[e];
    bc[h] = s + bih[h];
  }
}

// ---------------------------------------------------------------------------
// xproj GEMM: 128x128 tiles, XCD band remap, XOR-swizzled LDS.
// R9: depth-2 double-buffer (64KB LDS -> 2 blocks/CU for barrier overlap);
// vmcnt: 16 outstanding at loop top, vmcnt(8) drains chunk kk, kk+1 rides.
// R9: t=0 fold -- rows with tI==0 get tanh(v + bhh) = h0, written into xp[0].
// ---------------------------------------------------------------------------
__global__ __launch_bounds__(256) void gemm_xp(
    const u16* __restrict__ A, const u16* __restrict__ Bm,
    const float* __restrict__ bias, const float* __restrict__ bhh,
    u16* __restrict__ outp) {
  __shared__ __align__(16) u16 lds[32768];  // 2 x 16KB(A)+16KB(B)
  const int tid = threadIdx.x, lane = tid & 63, w = tid >> 6;
  const int lrow = lane >> 4, lcol = lane & 15;
  const int l7 = lane & 7, r8 = lane >> 3;
  const int p = blockIdx.x;
  const int xk = p & 7, q = p >> 3;
  const int mt = xk * 32 + (q >> 3), nt = q & 7;
  const int m0 = mt * 128, n0 = nt * 128;
  const int mq = (w & 1) * 64, nq = (w >> 1) * 64;
  const int half = w >> 1, wv = w & 1;  // waves 0,1 stage A; 2,3 stage B

  auto stage = [&](int kk, int d) {
    const u16* src = half ? Bm : A;
    const int rbase = half ? n0 : m0;
#pragma unroll
    for (int i = 0; i < 8; ++i) {
      int row = wv * 64 + i * 8 + r8;
      async_cp16(src + (size_t)(rbase + row) * H_DIM + kk * 64 + ((l7 ^ r8) << 3),
                 lds + d * 16384 + half * 8192 + (wv * 64 + i * 8) * 64);
    }
  };

  f32x4 acc[4][4] = {};
  auto kchunk = [&](int d) {
    const u16* base = lds + d * 16384;
#pragma unroll
    for (int ks = 0; ks < 2; ++ks) {
      const int ce = ks * 32 + lrow * 8;
      bf16x8 a[4], b[4];
#pragma unroll
      for (int i = 0; i < 4; ++i) {
        int row = mq + i * 16 + lcol;
        a[i] = *(const bf16x8*)(base + row * 64 + (ce ^ ((row & 7) << 3)));
      }
#pragma unroll
      for (int i = 0; i < 4; ++i) {
        int row = nq + i * 16 + lcol;
        b[i] = *(const bf16x8*)(base + 8192 + row * 64 + (ce ^ ((row & 7) << 3)));
      }
#pragma unroll
      for (int i = 0; i < 4; ++i)
#pragma unroll
        for (int j = 0; j < 4; ++j)
          acc[i][j] = __builtin_amdgcn_mfma_f32_16x16x32_bf16(a[i], b[j], acc[i][j], 0, 0, 0);
    }
  };

  stage(0, 0); stage(1, 1);
#pragma unroll
  for (int kk = 0; kk < 16; ++kk) {
    // 8 loads/thread/chunk; top-of-iter outstanding <= 16 (kk, kk+1)
    if (kk <= 14) asm volatile("s_waitcnt vmcnt(8)" ::: "memory");
    else          asm volatile("s_waitcnt vmcnt(0)" ::: "memory");
    __builtin_amdgcn_s_barrier();   // chunk kk LDS-visible to all waves
    kchunk(kk & 1);
    __builtin_amdgcn_s_barrier();   // all reads of buf kk&1 done
    if (kk <= 13) stage(kk + 2, kk & 1);
  }

  float bv[4], bh[4];
#pragma unroll
  for (int j = 0; j < 4; ++j) {
    bv[j] = bias[n0 + nq + j * 16 + lcol];
    bh[j] = bhh[n0 + nq + j * 16 + lcol];
  }
#pragma unroll
  for (int i = 0; i < 4; ++i)
#pragma unroll
    for (int rr = 0; rr < 4; ++rr) {
      int rg = m0 + mq + i * 16 + lrow * 4 + rr;  // flat (b*T + t)
      int bI = rg >> 5, tI = rg & 31;
      u16* dst = outp + ((size_t)tI * B_DIM + bI) * H_DIM + n0 + nq;
      if (tI == 0) {  // t=0 fold: h0 = tanh(x0 + bhh), full fp32 precision
#pragma unroll
        for (int j = 0; j < 4; ++j)
          dst[j * 16 + lcol] = f2bf(fast_tanh(acc[i][j][rr] + bv[j] + bh[j]));
      } else {
#pragma unroll
        for (int j = 0; j < 4; ++j)
          dst[j * 16 + lcol] = f2bf(acc[i][j][rr] + bv[j]);
      }
    }
}

// ---------------------------------------------------------------------------
// RNN step / output GEMM at 64x64 tiles, grid 256 (verified R7, untouched).
// Depth-3 counted-vmcnt, XOR-swizzled staging+reads, x-tile LDS-prefetch,
// LDS-assembled coalesced h-store. mt=(p&7)*2+(q>>4): writer XCD = reader XCD.
// MODE 1: h = tanh(A.Bm^T + bias + x), bf16. MODE 2: out = A.Bm^T+bias, f32.
// ---------------------------------------------------------------------------
template <int MODE>
__global__ __launch_bounds__(256) void step64(
    const u16* __restrict__ A, const u16* __restrict__ Bm,
    const u16* __restrict__ x, const float* __restrict__ bias,
    void* __restrict__ outp) {
  constexpr int XOFF = 24576;  // elems
  constexpr int LDSE = (MODE == 1) ? 28672 : 24576;
  __shared__ __align__(16) u16 lds[LDSE];
  const int tid = threadIdx.x, lane = tid & 63, w = tid >> 6;
  const int lrow = lane >> 4, lcol = lane & 15;
  const int l7 = lane & 7, r8 = lane >> 3;
  const int p = blockIdx.x;
  const int xcd = p & 7, q = p >> 3;          // q in 0..31
  const int mt = xcd * 2 + (q >> 4), nt = q & 15;
  const int m0 = mt * 64, n0 = nt * 64;
  const int mq = (w & 1) * 32, nq = (w >> 1) * 32;
  const int half = w >> 1, wv = w & 1;  // waves 0,1 stage A; 2,3 stage B

  auto stage = [&](int kk, int d) {
    const u16* src = half ? Bm : A;
    const int rbase = half ? n0 : m0;
#pragma unroll
    for (int i = 0; i < 4; ++i) {
      int row = wv * 32 + i * 8 + r8;  // tile-local
      async_cp16(src + (size_t)(rbase + row) * H_DIM + kk * 64 + ((l7 ^ r8) << 3),
                 lds + d * 8192 + half * 4096 + (wv * 32 + i * 8) * 64);
    }
  };
  auto stage_x = [&]() {  // 64x64 bf16 x-tile, linear
#pragma unroll
    for (int i = 0; i < 2; ++i)
      async_cp16(x + (size_t)(m0 + i * 32 + w * 8 + r8) * H_DIM + n0 + l7 * 8,
                 lds + XOFF + (i * 32 + w * 8) * 64);
  };

  f32x4 acc[2][2] = {};
  auto kchunk = [&](int d) {
    const u16* base = lds + d * 8192;
#pragma unroll
    for (int ks = 0; ks < 2; ++ks) {
      const int ce = ks * 32 + lrow * 8;
      bf16x8 a[2], b[2];
#pragma unroll
      for (int i = 0; i < 2; ++i) {
        int row = mq + i * 16 + lcol;
        a[i] = *(const bf16x8*)(base + row * 64 + (ce ^ ((row & 7) << 3)));
      }
#pragma unroll
      for (int j = 0; j < 2; ++j) {
        int row = nq + j * 16 + lcol;
        b[j] = *(const bf16x8*)(base + 4096 + row * 64 + (ce ^ ((row & 7) << 3)));
      }
#pragma unroll
      for (int i = 0; i < 2; ++i)
#pragma unroll
        for (int j = 0; j < 2; ++j)
          acc[i][j] = __builtin_amdgcn_mfma_f32_16x16x32_bf16(a[i], b[j], acc[i][j], 0, 0, 0);
    }
  };

  if (A != nullptr) {
    if (MODE == 1) stage_x();  // oldest in queue, drained by kk=0's wait
    stage(0, 0); stage(1, 1); stage(2, 2);
#pragma unroll
    for (int kk = 0; kk < 16; ++kk) {
      // 4 loads/thread/chunk; chunks kk+1, kk+2 stay in flight across barrier
      if (kk <= 13)      asm volatile("s_waitcnt vmcnt(8)" ::: "memory");
      else if (kk == 14) asm volatile("s_waitcnt vmcnt(4)" ::: "memory");
      else               asm volatile("s_waitcnt vmcnt(0)" ::: "memory");
      __builtin_amdgcn_s_barrier();   // chunk kk LDS-visible to all waves
      kchunk(kk % 3);
      __builtin_amdgcn_s_barrier();   // all reads of buf kk%3 done
      if (kk <= 12) stage(kk + 3, kk % 3);
    }
  } else {
    if (MODE == 1) stage_x();
    asm volatile("s_waitcnt vmcnt(0)" ::: "memory");
    __builtin_amdgcn_s_barrier();
  }

  float bv[2] = {bias[n0 + nq + lcol], bias[n0 + nq + 16 + lcol]};
  if (MODE == 2) {  // fp32 out, direct stores (once)
#pragma unroll
    for (int i = 0; i < 2; ++i)
#pragma unroll
      for (int rr = 0; rr < 4; ++rr) {
        int row = m0 + mq + i * 16 + lrow * 4 + rr;
#pragma unroll
        for (int j = 0; j < 2; ++j)
          ((float*)outp)[(size_t)row * O_DIM + n0 + nq + j * 16 + lcol] =
              acc[i][j][rr] + bv[j];
      }
  } else {  // MODE 1: h = tanh(acc + bias + x); assemble in LDS, coalesced out
#pragma unroll
    for (int i = 0; i < 2; ++i)
#pragma unroll
      for (int rr = 0; rr < 4; ++rr) {
        int rowl = mq + i * 16 + lrow * 4 + rr;  // tile-local
#pragma unroll
        for (int j = 0; j < 2; ++j) {
          int col = nq + j * 16 + lcol;
          float v = acc[i][j][rr] + bv[j] + bf2f(lds[XOFF + rowl * 64 + col]);
          lds[rowl * 64 + col] = f2bf(fast_tanh(v));  // buf0: reads done
        }
      }
    __syncthreads();
    {
      int row = tid >> 2, c = (tid & 3) * 16;  // 32 B/thread, coalesced
      const uint4* s = (const uint4*)(lds + row * 64 + c);
      uint4 v0 = s[0], v1 = s[1];
      uint4* g = (uint4*)((u16*)outp + (size_t)(m0 + row) * H_DIM + n0 + c);
      g[0] = v0;
      g[1] = v1;
    }
  }
}

// ---------------------------------------------------------------------------
// FALLBACK xproj (verified R5) for small workspace: fp32 A reg-staged.
// ---------------------------------------------------------------------------
__global__ __launch_bounds__(256) void xproj_mfma(
    const float* __restrict__ msg, const u16* __restrict__ Wc,
    const float* __restrict__ bc, u16* __restrict__ xp) {
  __shared__ u16 As[128 * 64];
  __shared__ u16 Bs[128 * 64];
  const int tid = threadIdx.x, lane = tid & 63, w = tid >> 6;
  const int lrow = lane >> 4, lcol = lane & 15;
  const int p = blockIdx.y * gridDim.x + blockIdx.x;
  const int xk = p & 7, q = p >> 3;
  const int m0 = (xk * 32 + (q >> 3)) * 128;
  const int n0 = (q & 7) * 128;
  const int mq = (w & 1) * 64, nq = (w >> 1) * 64;
  f32x4 acc[4][4] = {};
  const int r8 = lane >> 3, l7 = lane & 7;
  const int ar = tid >> 1, ak = (tid & 1) * 32;

  auto stageB = [&](int kk) {
#pragma unroll
    for (int i = 0; i < 4; ++i) {
      int ch = w * 4 + i;
      async_cp16(Wc + (size_t)(n0 + ch * 8 + r8) * V_DIM + kk * 64 + ((l7 ^ r8) << 3),
                 Bs + ch * 512);
    }
  };
  float4 areg[8];
  auto loadA = [&](int kk) {
    const float4* src = (const float4*)(msg + (size_t)(m0 + ar) * V_DIM + kk * 64 + ak);
#pragma unroll
    for (int i = 0; i < 8; ++i) areg[i] = src[i];
  };
  auto writeA = [&]() {
    u16 tmp[32];
#pragma unroll
    for (int i = 0; i < 8; ++i) {
      tmp[i * 4 + 0] = f2bf(areg[i].x);
      tmp[i * 4 + 1] = f2bf(areg[i].y);
      tmp[i * 4 + 2] = f2bf(areg[i].z);
      tmp[i * 4 + 3] = f2bf(areg[i].w);
    }
#pragma unroll
    for (int i = 0; i < 4; ++i) {
      int c = (ak + i * 8) ^ ((ar & 7) << 3);
      *(uint4*)(As + (size_t)ar * 64 + c) = *(const uint4*)(tmp + i * 8);
    }
  };

  loadA(0);
  stageB(0);
  writeA();
  for (int kk = 0; kk < 16; ++kk) {
    __syncthreads();
    if (kk < 15) loadA(kk + 1);
#pragma unroll
    for (int ks = 0; ks < 2; ++ks) {
      const int kb = ks * 32 + lrow * 8;
      bf16x8 a[4], b[4];
#pragma unroll
      for (int i = 0; i < 4; ++i) {
        int row = mq + i * 16 + lcol;
        a[i] = *(const bf16x8*)(As + row * 64 + (kb ^ ((row & 7) << 3)));
      }
#pragma unroll
      for (int i = 0; i < 4; ++i) {
        int row = nq + i * 16 + lcol;
        b[i] = *(const bf16x8*)(Bs + row * 64 + (kb ^ ((row & 7) << 3)));
      }
#pragma unroll
      for (int i = 0; i < 4; ++i)
#pragma unroll
        for (int j = 0; j < 4; ++j)
          acc[i][j] = __builtin_amdgcn_mfma_f32_16x16x32_bf16(a[i], b[j], acc[i][j], 0, 0, 0);
    }
    __syncthreads();
    if (kk < 15) { stageB(kk + 1); writeA(); }
  }
  float bcv[4];
#pragma unroll
  for (int j = 0; j < 4; ++j) bcv[j] = bc[n0 + nq + j * 16 + lcol];
#pragma unroll
  for (int i = 0; i < 4; ++i)
#pragma unroll
    for (int rr = 0; rr < 4; ++rr) {
      int rg = m0 + mq + i * 16 + lrow * 4 + rr;
      int bI = rg >> 5, tI = rg & 31;
      u16* dst = xp + ((size_t)tI * B_DIM + bI) * H_DIM + n0 + nq;
#pragma unroll
      for (int j = 0; j < 4; ++j)
        dst[j * 16 + lcol] = f2bf(acc[i][j][rr] + bcv[j]);
    }
}

// ---------------------------------------------------------------------------
extern "C" void kernel_launch(void* const* d_in, const int* in_sizes, int n_in,
                              void* d_out, int out_size, void* d_ws, size_t ws_size,
                              hipStream_t stream) {
  const float* msg  = (const float*)d_in[0];
  const float* Wemb = (const float*)d_in[1];
  const float* bemb = (const float*)d_in[2];
  const float* Wih  = (const float*)d_in[3];
  const float* bih  = (const float*)d_in[4];
  const float* Whh  = (const float*)d_in[5];
  const float* bhh  = (const float*)d_in[6];
  const float* Wout = (const float*)d_in[7];
  const float* bout = (const float*)d_in[8];
  char* ws = (char*)d_ws;

  // ws layout (bytes)
  float* bc   = (float*)ws;               // 4 KB
  u16* Wc     = (u16*)(ws + 4096);        // 2 MB
  u16* Whh_b  = (u16*)(ws + 2101248);     // 2 MB
  u16* Wout_b = (u16*)(ws + 4198400);     // 2 MB
  u16* hA     = (u16*)(ws + 6295552);     // 2 MB
  u16* hB     = (u16*)(ws + 8392704);     // 2 MB
  u16* xp     = (u16*)(ws + 10489856);    // 64 MB
  u16* msgb   = (u16*)(ws + 77598720);    // 64 MB (only if ws big enough)
  const size_t NEED_SMALL = 77598720;
  const size_t NEED_BIG   = 77598720 + 67108864;
  if (ws_size < NEED_SMALL) return;
  const bool big = ws_size >= NEED_BIG;

  prep_all<<<2308, 256, 0, stream>>>(Whh, Wout, big ? msg : nullptr, Wih, Wemb,
                                     bemb, bih, Whh_b, Wout_b,
                                     big ? msgb : nullptr, Wc, bc);

  if (big) {
    // xproj + t=0 fold: rows tI==0 get tanh(v+bhh) -> h0 lands in xp slot 0
    gemm_xp<<<2048, 256, 0, stream>>>(msgb, Wc, bc, bhh, xp);
    // t=1 reads h0 from xp slot 0, writes hB; then ping-pong (odd->hB, even->hA)
    step64<1><<<256, 256, 0, stream>>>(xp, Whh_b,
                                       xp + (size_t)1 * B_DIM * H_DIM, bhh, hB);
    for (int t = 2; t < 32; ++t) {
      const u16* hin = (t & 1) ? hA : hB;
      u16* hout = (t & 1) ? hB : hA;
      step64<1><<<256, 256, 0, stream>>>(hin, Whh_b,
                                         xp + (size_t)t * B_DIM * H_DIM, bhh, hout);
    }
  } else {
    xproj_mfma<<<dim3(8, 256), 256, 0, stream>>>(msg, Wc, bc, xp);
    step64<1><<<256, 256, 0, stream>>>(nullptr, Whh_b, xp, bhh, hA);
    for (int t = 1; t < 32; ++t) {
      const u16* hin = (t & 1) ? hA : hB;
      u16* hout = (t & 1) ? hB : hA;
      step64<1><<<256, 256, 0, stream>>>(hin, Whh_b,
                                         xp + (size_t)t * B_DIM * H_DIM, bhh, hout);
    }
  }
  // out = h_T . W_out^T + b_out  (h_T in hB after t=31), fp32 out
  step64<2><<<256, 256, 0, stream>>>(hB, Wout_b, nullptr, bout, d_out);
}

// Round 10
// 509.097 us; speedup vs baseline: 1.5200x; 1.0741x over previous
//
#include <hip/hip_runtime.h>
#include <cstdint>
#include <cstddef>

// Problem dims (fixed). Inputs fp32, output fp32.
#define B_DIM 1024
#define T_DIM 32
#define V_DIM 1024
#define E_DIM 512
#define H_DIM 1024
#define O_DIM 1024

typedef unsigned short u16;
typedef __attribute__((ext_vector_type(8))) __bf16 bf16x8;  // MFMA A/B frag
typedef __attribute__((ext_vector_type(4))) float f32x4;    // MFMA C/D frag

__device__ __forceinline__ float bf2f(u16 u) {
  union { unsigned int i; float f; } v; v.i = ((unsigned int)u) << 16; return v.f;
}
__device__ __forceinline__ u16 f2bf(float f) {
  union { float f; unsigned int i; } v; v.f = f;
  return (u16)((v.i + 0x7fffu + ((v.i >> 16) & 1u)) >> 16);  // RNE
}
// async global->LDS, 16B/lane; HW writes lds_base + lane*16 (wave-uniform base)
__device__ __forceinline__ void async_cp16(const void* g, void* l) {
  __builtin_amdgcn_global_load_lds(
      (const __attribute__((address_space(1))) void*)g,
      (__attribute__((address_space(3))) void*)l, 16, 0, 0);
}
// fast tanh via hw exp+rcp: exact at +-inf, |err| ~1e-6 (<< bf16 ulp)
__device__ __forceinline__ float fast_tanh(float v) {
  return 1.f - 2.f / (__expf(2.f * v) + 1.f);
}

// ---------------------------------------------------------------------------
// Fused prep (memory work ONLY -- the old fp32-VALU wcomb is gone, replaced
// by wcomb_mfma below):
//  blocks [0,2048):    convert msg/W_hh/W_out fp32->bf16 (grid-stride)
//  blocks [2048,2176): W_ih -> A3 = [hi | lo | hi]  (1024 x 1536 bf16)
//  blocks [2176,2304): W_emb -> B3 = [hi | hi | lo] transposed (1024 x 1536)
//  blocks [2304,2308): bcomb
// hi/lo split: w = hi + lo + O(2^-18 w)  ->  A3.B3^T = hihi + lohi + hilo
// (missing lolo ~ 2^-18, far below bf16(Wc) rounding).
// ---------------------------------------------------------------------------
__global__ __launch_bounds__(256) void prep_all(
    const float* __restrict__ Whh, const float* __restrict__ Wout,
    const float* __restrict__ msg, const float* __restrict__ Wih,
    const float* __restrict__ Wemb, const float* __restrict__ bemb,
    const float* __restrict__ bih, u16* __restrict__ dWhh,
    u16* __restrict__ dWout, u16* __restrict__ dmsg,
    u16* __restrict__ A3, u16* __restrict__ B3, float* __restrict__ bc) {
  __shared__ __align__(16) float T[64][65];
  const int bid = blockIdx.x, tid = threadIdx.x;
  if (bid < 2048) {  // ---- convert (pure BW) ----
    const int QW = 262144;            // 1M elems / 4
    const int QM = 8388608;           // 32M elems / 4
    const int total = dmsg ? (2 * QW + QM) : (2 * QW);
    int i = bid * 256 + tid;
    const int stride = 2048 * 256;
    for (; i < total; i += stride) {
      const float4* src; ushort4* dst; int j;
      if (i < QW)          { src = (const float4*)Whh;  dst = (ushort4*)dWhh;  j = i; }
      else if (i < 2 * QW) { src = (const float4*)Wout; dst = (ushort4*)dWout; j = i - QW; }
      else                 { src = (const float4*)msg;  dst = (ushort4*)dmsg;  j = i - 2 * QW; }
      float4 v = src[j];
      ushort4 o = {f2bf(v.x), f2bf(v.y), f2bf(v.z), f2bf(v.w)};
      dst[j] = o;
    }
  } else if (bid < 2176) {  // ---- W_ih -> A3 [hi|lo|hi] ----
    const int b8 = bid - 2048;  // 0..127, 8 rows each
    const float4* W4 = (const float4*)Wih;
#pragma unroll
    for (int it = 0; it < 4; ++it) {
      int i = it * 256 + tid;            // 0..1023
      int r = b8 * 8 + (i >> 7), c4 = i & 127;
      float4 v = W4[(size_t)r * 128 + c4];
      ushort4 hi = {f2bf(v.x), f2bf(v.y), f2bf(v.z), f2bf(v.w)};
      ushort4 lo = {f2bf(v.x - bf2f(hi.x)), f2bf(v.y - bf2f(hi.y)),
                    f2bf(v.z - bf2f(hi.z)), f2bf(v.w - bf2f(hi.w))};
      u16* base = A3 + (size_t)r * 1536 + c4 * 4;
      *(ushort4*)(base)        = hi;
      *(ushort4*)(base + 512)  = lo;
      *(ushort4*)(base + 1024) = hi;
    }
  } else if (bid < 2304) {  // ---- W_emb transpose -> B3 [hi|hi|lo] ----
    const int b = bid - 2176;                    // 0..127
    const int e0 = (b >> 4) * 64, v0 = (b & 15) * 64;
#pragma unroll
    for (int ps = 0; ps < 16; ++ps) {
      int r = ps * 4 + (tid >> 6), c = tid & 63;
      T[r][c] = Wemb[(size_t)(e0 + r) * V_DIM + v0 + c];
    }
    __syncthreads();
#pragma unroll
    for (int ps = 0; ps < 16; ++ps) {
      int vr = ps * 4 + (tid >> 6), ec = tid & 63;
      float wv = T[ec][vr];                      // transposed read, stride 65
      u16 hi = f2bf(wv);
      u16 lo = f2bf(wv - bf2f(hi));
      u16* base = B3 + (size_t)(v0 + vr) * 1536 + e0 + ec;
      base[0]    = hi;
      base[512]  = hi;
      base[1024] = lo;
    }
  } else {  // ---- bcomb ----
    int h = (bid - 2304) * 256 + tid;
    float s = 0.f;
    for (int e = 0; e < E_DIM; ++e) s += Wih[(size_t)h * E_DIM + e] * bemb[e];
    bc[h] = s + bih[h];
  }
}

// ---------------------------------------------------------------------------
// W_comb via MFMA: Wc[h][v] = A3[h,:].B3[v,:] (K=1536 = hihi+lohi+hilo).
// step64-verified machinery: 64x64 tiles, grid 256, depth-3 counted vmcnt,
// XOR-swizzled staging+reads. ~24 K-chunks.
// ---------------------------------------------------------------------------
__global__ __launch_bounds__(256) void wcomb_mfma(
    const u16* __restrict__ A3, const u16* __restrict__ B3,
    u16* __restrict__ Wc) {
  __shared__ __align__(16) u16 lds[24576];  // 3 x 8KB
  const int tid = threadIdx.x, lane = tid & 63, w = tid >> 6;
  const int lrow = lane >> 4, lcol = lane & 15;
  const int l7 = lane & 7, r8 = lane >> 3;
  const int p = blockIdx.x;
  const int xcd = p & 7, q = p >> 3;
  const int mt = xcd * 2 + (q >> 4), nt = q & 15;
  const int m0 = mt * 64, n0 = nt * 64;  // m0 = h band, n0 = v band
  const int mq = (w & 1) * 32, nq = (w >> 1) * 32;
  const int half = w >> 1, wv = w & 1;

  auto stage = [&](int kk, int d) {
    const u16* src = half ? B3 : A3;
    const int rbase = half ? n0 : m0;
#pragma unroll
    for (int i = 0; i < 4; ++i) {
      int row = wv * 32 + i * 8 + r8;
      async_cp16(src + (size_t)(rbase + row) * 1536 + kk * 64 + ((l7 ^ r8) << 3),
                 lds + d * 8192 + half * 4096 + (wv * 32 + i * 8) * 64);
    }
  };
  f32x4 acc[2][2] = {};
  auto kchunk = [&](int d) {
    const u16* base = lds + d * 8192;
#pragma unroll
    for (int ks = 0; ks < 2; ++ks) {
      const int ce = ks * 32 + lrow * 8;
      int rA0 = mq + lcol, rA1 = mq + 16 + lcol;
      int rB0 = nq + lcol, rB1 = nq + 16 + lcol;
      bf16x8 a0 = *(const bf16x8*)(base + rA0 * 64 + (ce ^ ((rA0 & 7) << 3)));
      bf16x8 a1 = *(const bf16x8*)(base + rA1 * 64 + (ce ^ ((rA1 & 7) << 3)));
      bf16x8 b0 = *(const bf16x8*)(base + 4096 + rB0 * 64 + (ce ^ ((rB0 & 7) << 3)));
      bf16x8 b1 = *(const bf16x8*)(base + 4096 + rB1 * 64 + (ce ^ ((rB1 & 7) << 3)));
      acc[0][0] = __builtin_amdgcn_mfma_f32_16x16x32_bf16(a0, b0, acc[0][0], 0, 0, 0);
      acc[0][1] = __builtin_amdgcn_mfma_f32_16x16x32_bf16(a0, b1, acc[0][1], 0, 0, 0);
      acc[1][0] = __builtin_amdgcn_mfma_f32_16x16x32_bf16(a1, b0, acc[1][0], 0, 0, 0);
      acc[1][1] = __builtin_amdgcn_mfma_f32_16x16x32_bf16(a1, b1, acc[1][1], 0, 0, 0);
    }
  };
  stage(0, 0); stage(1, 1); stage(2, 2);
#pragma unroll
  for (int kk = 0; kk < 24; ++kk) {
    if (kk <= 21)      asm volatile("s_waitcnt vmcnt(8)" ::: "memory");
    else if (kk == 22) asm volatile("s_waitcnt vmcnt(4)" ::: "memory");
    else               asm volatile("s_waitcnt vmcnt(0)" ::: "memory");
    __builtin_amdgcn_s_barrier();
    kchunk(kk % 3);
    __builtin_amdgcn_s_barrier();
    if (kk <= 20) stage(kk + 3, kk % 3);
  }
#pragma unroll
  for (int i = 0; i < 2; ++i)
#pragma unroll
    for (int rr = 0; rr < 4; ++rr) {
      int hrow = m0 + mq + i * 16 + lrow * 4 + rr;
#pragma unroll
      for (int j = 0; j < 2; ++j)
        Wc[(size_t)hrow * V_DIM + n0 + nq + j * 16 + lcol] = f2bf(acc[i][j][rr]);
    }
}

// ---------------------------------------------------------------------------
// xproj GEMM (R9-verified): 128x128 tiles, XCD band remap, XOR-swizzled LDS,
// depth-2 double-buffer (64KB LDS -> 2 blocks/CU), t=0 fold into epilogue.
// ---------------------------------------------------------------------------
__global__ __launch_bounds__(256) void gemm_xp(
    const u16* __restrict__ A, const u16* __restrict__ Bm,
    const float* __restrict__ bias, const float* __restrict__ bhh,
    u16* __restrict__ outp) {
  __shared__ __align__(16) u16 lds[32768];  // 2 x 16KB(A)+16KB(B)
  const int tid = threadIdx.x, lane = tid & 63, w = tid >> 6;
  const int lrow = lane >> 4, lcol = lane & 15;
  const int l7 = lane & 7, r8 = lane >> 3;
  const int p = blockIdx.x;
  const int xk = p & 7, q = p >> 3;
  const int mt = xk * 32 + (q >> 3), nt = q & 7;
  const int m0 = mt * 128, n0 = nt * 128;
  const int mq = (w & 1) * 64, nq = (w >> 1) * 64;
  const int half = w >> 1, wv = w & 1;  // waves 0,1 stage A; 2,3 stage B

  auto stage = [&](int kk, int d) {
    const u16* src = half ? Bm : A;
    const int rbase = half ? n0 : m0;
#pragma unroll
    for (int i = 0; i < 8; ++i) {
      int row = wv * 64 + i * 8 + r8;
      async_cp16(src + (size_t)(rbase + row) * H_DIM + kk * 64 + ((l7 ^ r8) << 3),
                 lds + d * 16384 + half * 8192 + (wv * 64 + i * 8) * 64);
    }
  };

  f32x4 acc[4][4] = {};
  auto kchunk = [&](int d) {
    const u16* base = lds + d * 16384;
#pragma unroll
    for (int ks = 0; ks < 2; ++ks) {
      const int ce = ks * 32 + lrow * 8;
      bf16x8 a[4], b[4];
#pragma unroll
      for (int i = 0; i < 4; ++i) {
        int row = mq + i * 16 + lcol;
        a[i] = *(const bf16x8*)(base + row * 64 + (ce ^ ((row & 7) << 3)));
      }
#pragma unroll
      for (int i = 0; i < 4; ++i) {
        int row = nq + i * 16 + lcol;
        b[i] = *(const bf16x8*)(base + 8192 + row * 64 + (ce ^ ((row & 7) << 3)));
      }
#pragma unroll
      for (int i = 0; i < 4; ++i)
#pragma unroll
        for (int j = 0; j < 4; ++j)
          acc[i][j] = __builtin_amdgcn_mfma_f32_16x16x32_bf16(a[i], b[j], acc[i][j], 0, 0, 0);
    }
  };

  stage(0, 0); stage(1, 1);
#pragma unroll
  for (int kk = 0; kk < 16; ++kk) {
    // 8 loads/thread/chunk; top-of-iter outstanding <= 16 (kk, kk+1)
    if (kk <= 14) asm volatile("s_waitcnt vmcnt(8)" ::: "memory");
    else          asm volatile("s_waitcnt vmcnt(0)" ::: "memory");
    __builtin_amdgcn_s_barrier();   // chunk kk LDS-visible to all waves
    kchunk(kk & 1);
    __builtin_amdgcn_s_barrier();   // all reads of buf kk&1 done
    if (kk <= 13) stage(kk + 2, kk & 1);
  }

  float bv[4], bh[4];
#pragma unroll
  for (int j = 0; j < 4; ++j) {
    bv[j] = bias[n0 + nq + j * 16 + lcol];
    bh[j] = bhh[n0 + nq + j * 16 + lcol];
  }
#pragma unroll
  for (int i = 0; i < 4; ++i)
#pragma unroll
    for (int rr = 0; rr < 4; ++rr) {
      int rg = m0 + mq + i * 16 + lrow * 4 + rr;  // flat (b*T + t)
      int bI = rg >> 5, tI = rg & 31;
      u16* dst = outp + ((size_t)tI * B_DIM + bI) * H_DIM + n0 + nq;
      if (tI == 0) {  // t=0 fold: h0 = tanh(x0 + bhh), full fp32 precision
#pragma unroll
        for (int j = 0; j < 4; ++j)
          dst[j * 16 + lcol] = f2bf(fast_tanh(acc[i][j][rr] + bv[j] + bh[j]));
      } else {
#pragma unroll
        for (int j = 0; j < 4; ++j)
          dst[j * 16 + lcol] = f2bf(acc[i][j][rr] + bv[j]);
      }
    }
}

// ---------------------------------------------------------------------------
// RNN step / output GEMM at 64x64 tiles, grid 256 (verified R7, untouched).
// Depth-3 counted-vmcnt, XOR-swizzled staging+reads, x-tile LDS-prefetch,
// LDS-assembled coalesced h-store. mt=(p&7)*2+(q>>4): writer XCD = reader XCD.
// MODE 1: h = tanh(A.Bm^T + bias + x), bf16. MODE 2: out = A.Bm^T+bias, f32.
// ---------------------------------------------------------------------------
template <int MODE>
__global__ __launch_bounds__(256) void step64(
    const u16* __restrict__ A, const u16* __restrict__ Bm,
    const u16* __restrict__ x, const float* __restrict__ bias,
    void* __restrict__ outp) {
  constexpr int XOFF = 24576;  // elems
  constexpr int LDSE = (MODE == 1) ? 28672 : 24576;
  __shared__ __align__(16) u16 lds[LDSE];
  const int tid = threadIdx.x, lane = tid & 63, w = tid >> 6;
  const int lrow = lane >> 4, lcol = lane & 15;
  const int l7 = lane & 7, r8 = lane >> 3;
  const int p = blockIdx.x;
  const int xcd = p & 7, q = p >> 3;          // q in 0..31
  const int mt = xcd * 2 + (q >> 4), nt = q & 15;
  const int m0 = mt * 64, n0 = nt * 64;
  const int mq = (w & 1) * 32, nq = (w >> 1) * 32;
  const int half = w >> 1, wv = w & 1;  // waves 0,1 stage A; 2,3 stage B

  auto stage = [&](int kk, int d) {
    const u16* src = half ? Bm : A;
    const int rbase = half ? n0 : m0;
#pragma unroll
    for (int i = 0; i < 4; ++i) {
      int row = wv * 32 + i * 8 + r8;  // tile-local
      async_cp16(src + (size_t)(rbase + row) * H_DIM + kk * 64 + ((l7 ^ r8) << 3),
                 lds + d * 8192 + half * 4096 + (wv * 32 + i * 8) * 64);
    }
  };
  auto stage_x = [&]() {  // 64x64 bf16 x-tile, linear
#pragma unroll
    for (int i = 0; i < 2; ++i)
      async_cp16(x + (size_t)(m0 + i * 32 + w * 8 + r8) * H_DIM + n0 + l7 * 8,
                 lds + XOFF + (i * 32 + w * 8) * 64);
  };

  f32x4 acc[2][2] = {};
  auto kchunk = [&](int d) {
    const u16* base = lds + d * 8192;
#pragma unroll
    for (int ks = 0; ks < 2; ++ks) {
      const int ce = ks * 32 + lrow * 8;
      bf16x8 a[2], b[2];
#pragma unroll
      for (int i = 0; i < 2; ++i) {
        int row = mq + i * 16 + lcol;
        a[i] = *(const bf16x8*)(base + row * 64 + (ce ^ ((row & 7) << 3)));
      }
#pragma unroll
      for (int j = 0; j < 2; ++j) {
        int row = nq + j * 16 + lcol;
        b[j] = *(const bf16x8*)(base + 4096 + row * 64 + (ce ^ ((row & 7) << 3)));
      }
#pragma unroll
      for (int i = 0; i < 2; ++i)
#pragma unroll
        for (int j = 0; j < 2; ++j)
          acc[i][j] = __builtin_amdgcn_mfma_f32_16x16x32_bf16(a[i], b[j], acc[i][j], 0, 0, 0);
    }
  };

  if (A != nullptr) {
    if (MODE == 1) stage_x();  // oldest in queue, drained by kk=0's wait
    stage(0, 0); stage(1, 1); stage(2, 2);
#pragma unroll
    for (int kk = 0; kk < 16; ++kk) {
      // 4 loads/thread/chunk; chunks kk+1, kk+2 stay in flight across barrier
      if (kk <= 13)      asm volatile("s_waitcnt vmcnt(8)" ::: "memory");
      else if (kk == 14) asm volatile("s_waitcnt vmcnt(4)" ::: "memory");
      else               asm volatile("s_waitcnt vmcnt(0)" ::: "memory");
      __builtin_amdgcn_s_barrier();   // chunk kk LDS-visible to all waves
      kchunk(kk % 3);
      __builtin_amdgcn_s_barrier();   // all reads of buf kk%3 done
      if (kk <= 12) stage(kk + 3, kk % 3);
    }
  } else {
    if (MODE == 1) stage_x();
    asm volatile("s_waitcnt vmcnt(0)" ::: "memory");
    __builtin_amdgcn_s_barrier();
  }

  float bv[2] = {bias[n0 + nq + lcol], bias[n0 + nq + 16 + lcol]};
  if (MODE == 2) {  // fp32 out, direct stores (once)
#pragma unroll
    for (int i = 0; i < 2; ++i)
#pragma unroll
      for (int rr = 0; rr < 4; ++rr) {
        int row = m0 + mq + i * 16 + lrow * 4 + rr;
#pragma unroll
        for (int j = 0; j < 2; ++j)
          ((float*)outp)[(size_t)row * O_DIM + n0 + nq + j * 16 + lcol] =
              acc[i][j][rr] + bv[j];
      }
  } else {  // MODE 1: h = tanh(acc + bias + x); assemble in LDS, coalesced out
#pragma unroll
    for (int i = 0; i < 2; ++i)
#pragma unroll
      for (int rr = 0; rr < 4; ++rr) {
        int rowl = mq + i * 16 + lrow * 4 + rr;  // tile-local
#pragma unroll
        for (int j = 0; j < 2; ++j) {
          int col = nq + j * 16 + lcol;
          float v = acc[i][j][rr] + bv[j] + bf2f(lds[XOFF + rowl * 64 + col]);
          lds[rowl * 64 + col] = f2bf(fast_tanh(v));  // buf0: reads done
        }
      }
    __syncthreads();
    {
      int row = tid >> 2, c = (tid & 3) * 16;  // 32 B/thread, coalesced
      const uint4* s = (const uint4*)(lds + row * 64 + c);
      uint4 v0 = s[0], v1 = s[1];
      uint4* g = (uint4*)((u16*)outp + (size_t)(m0 + row) * H_DIM + n0 + c);
      g[0] = v0;
      g[1] = v1;
    }
  }
}

// ---------------------------------------------------------------------------
// FALLBACK xproj (verified R5) for small workspace: fp32 A reg-staged.
// ---------------------------------------------------------------------------
__global__ __launch_bounds__(256) void xproj_mfma(
    const float* __restrict__ msg, const u16* __restrict__ Wc,
    const float* __restrict__ bc, u16* __restrict__ xp) {
  __shared__ u16 As[128 * 64];
  __shared__ u16 Bs[128 * 64];
  const int tid = threadIdx.x, lane = tid & 63, w = tid >> 6;
  const int lrow = lane >> 4, lcol = lane & 15;
  const int p = blockIdx.y * gridDim.x + blockIdx.x;
  const int xk = p & 7, q = p >> 3;
  const int m0 = (xk * 32 + (q >> 3)) * 128;
  const int n0 = (q & 7) * 128;
  const int mq = (w & 1) * 64, nq = (w >> 1) * 64;
  f32x4 acc[4][4] = {};
  const int r8 = lane >> 3, l7 = lane & 7;
  const int ar = tid >> 1, ak = (tid & 1) * 32;

  auto stageB = [&](int kk) {
#pragma unroll
    for (int i = 0; i < 4; ++i) {
      int ch = w * 4 + i;
      async_cp16(Wc + (size_t)(n0 + ch * 8 + r8) * V_DIM + kk * 64 + ((l7 ^ r8) << 3),
                 Bs + ch * 512);
    }
  };
  float4 areg[8];
  auto loadA = [&](int kk) {
    const float4* src = (const float4*)(msg + (size_t)(m0 + ar) * V_DIM + kk * 64 + ak);
#pragma unroll
    for (int i = 0; i < 8; ++i) areg[i] = src[i];
  };
  auto writeA = [&]() {
    u16 tmp[32];
#pragma unroll
    for (int i = 0; i < 8; ++i) {
      tmp[i * 4 + 0] = f2bf(areg[i].x);
      tmp[i * 4 + 1] = f2bf(areg[i].y);
      tmp[i * 4 + 2] = f2bf(areg[i].z);
      tmp[i * 4 + 3] = f2bf(areg[i].w);
    }
#pragma unroll
    for (int i = 0; i < 4; ++i) {
      int c = (ak + i * 8) ^ ((ar & 7) << 3);
      *(uint4*)(As + (size_t)ar * 64 + c) = *(const uint4*)(tmp + i * 8);
    }
  };

  loadA(0);
  stageB(0);
  writeA();
  for (int kk = 0; kk < 16; ++kk) {
    __syncthreads();
    if (kk < 15) loadA(kk + 1);
#pragma unroll
    for (int ks = 0; ks < 2; ++ks) {
      const int kb = ks * 32 + lrow * 8;
      bf16x8 a[4], b[4];
#pragma unroll
      for (int i = 0; i < 4; ++i) {
        int row = mq + i * 16 + lcol;
        a[i] = *(const bf16x8*)(As + row * 64 + (kb ^ ((row & 7) << 3)));
      }
#pragma unroll
      for (int i = 0; i < 4; ++i) {
        int row = nq + i * 16 + lcol;
        b[i] = *(const bf16x8*)(Bs + row * 64 + (kb ^ ((row & 7) << 3)));
      }
#pragma unroll
      for (int i = 0; i < 4; ++i)
#pragma unroll
        for (int j = 0; j < 4; ++j)
          acc[i][j] = __builtin_amdgcn_mfma_f32_16x16x32_bf16(a[i], b[j], acc[i][j], 0, 0, 0);
    }
    __syncthreads();
    if (kk < 15) { stageB(kk + 1); writeA(); }
  }
  float bcv[4];
#pragma unroll
  for (int j = 0; j < 4; ++j) bcv[j] = bc[n0 + nq + j * 16 + lcol];
#pragma unroll
  for (int i = 0; i < 4; ++i)
#pragma unroll
    for (int rr = 0; rr < 4; ++rr) {
      int rg = m0 + mq + i * 16 + lrow * 4 + rr;
      int bI = rg >> 5, tI = rg & 31;
      u16* dst = xp + ((size_t)tI * B_DIM + bI) * H_DIM + n0 + nq;
#pragma unroll
      for (int j = 0; j < 4; ++j)
        dst[j * 16 + lcol] = f2bf(acc[i][j][rr] + bcv[j]);
    }
}

// ---------------------------------------------------------------------------
extern "C" void kernel_launch(void* const* d_in, const int* in_sizes, int n_in,
                              void* d_out, int out_size, void* d_ws, size_t ws_size,
                              hipStream_t stream) {
  const float* msg  = (const float*)d_in[0];
  const float* Wemb = (const float*)d_in[1];
  const float* bemb = (const float*)d_in[2];
  const float* Wih  = (const float*)d_in[3];
  const float* bih  = (const float*)d_in[4];
  const float* Whh  = (const float*)d_in[5];
  const float* bhh  = (const float*)d_in[6];
  const float* Wout = (const float*)d_in[7];
  const float* bout = (const float*)d_in[8];
  char* ws = (char*)d_ws;

  // ws layout (bytes)
  float* bc   = (float*)ws;               // 4 KB
  u16* Wc     = (u16*)(ws + 4096);        // 2 MB
  u16* Whh_b  = (u16*)(ws + 2101248);     // 2 MB
  u16* Wout_b = (u16*)(ws + 4198400);     // 2 MB
  u16* hA     = (u16*)(ws + 6295552);     // 2 MB
  u16* hB     = (u16*)(ws + 8392704);     // 2 MB
  u16* xp     = (u16*)(ws + 10489856);    // 64 MB
  u16* msgb   = (u16*)(ws + 77598720);    // 64 MB (only if ws big enough)
  // A3/B3 (3 MB each) transiently occupy the START of the xp region: they are
  // fully consumed by wcomb_mfma BEFORE gemm_xp/xproj overwrites xp.
  u16* A3     = (u16*)(ws + 10489856);
  u16* B3     = (u16*)(ws + 10489856 + 3145728);
  const size_t NEED_SMALL = 77598720;
  const size_t NEED_BIG   = 77598720 + 67108864;
  if (ws_size < NEED_SMALL) return;
  const bool big = ws_size >= NEED_BIG;

  prep_all<<<2308, 256, 0, stream>>>(Whh, Wout, big ? msg : nullptr, Wih, Wemb,
                                     bemb, bih, Whh_b, Wout_b,
                                     big ? msgb : nullptr, A3, B3, bc);
  wcomb_mfma<<<256, 256, 0, stream>>>(A3, B3, Wc);

  if (big) {
    // xproj + t=0 fold: rows tI==0 get tanh(v+bhh) -> h0 lands in xp slot 0
    gemm_xp<<<2048, 256, 0, stream>>>(msgb, Wc, bc, bhh, xp);
    // t=1 reads h0 from xp slot 0, writes hB; then ping-pong (odd->hB, even->hA)
    step64<1><<<256, 256, 0, stream>>>(xp, Whh_b,
                                       xp + (size_t)1 * B_DIM * H_DIM, bhh, hB);
    for (int t = 2; t < 32; ++t) {
      const u16* hin = (t & 1) ? hA : hB;
      u16* hout = (t & 1) ? hB : hA;
      step64<1><<<256, 256, 0, stream>>>(hin, Whh_b,
                                         xp + (size_t)t * B_DIM * H_DIM, bhh, hout);
    }
  } else {
    xproj_mfma<<<dim3(8, 256), 256, 0, stream>>>(msg, Wc, bc, xp);
    step64<1><<<256, 256, 0, stream>>>(nullptr, Whh_b, xp, bhh, hA);
    for (int t = 1; t < 32; ++t) {
      const u16* hin = (t & 1) ? hA : hB;
      u16* hout = (t & 1) ? hB : hA;
      step64<1><<<256, 256, 0, stream>>>(hin, Whh_b,
                                         xp + (size_t)t * B_DIM * H_DIM, bhh, hout);
    }
  }
  // out = h_T . W_out^T + b_out  (h_T in hB after t=31), fp32 out
  step64<2><<<256, 256, 0, stream>>>(hB, Wout_b, nullptr, bout, d_out);
}